// Round 5
// baseline (113.173 us; speedup 1.0000x reference)
//
#include <hip/hip_runtime.h>
#include <hip/hip_fp16.h>

#define BATCH 8192
#define NNB 100
#define NDEV 1000000

// Projected-table geometry: 2885 rows (lang 50, plat 5, os 30, country 200,
// carrier 500, brand 2000, plat_os 100), 67 output dims per row.
// Interleaved layout: g_P2*[row*64 + l] = {f16 P[row][l], f16 P[row][64+l]}
// (high half exact 0 for l>=3).
#define NROWS 2885
#define NP2HALF (NROWS * 64)   // 184640

// Static device storage (graph-capture safe).
__device__ __half2 g_P2msg[NP2HALF];
__device__ __half2 g_P2dev1[NP2HALF];
__device__ float g_w0b_msg[256];    // [0:67]=W[:,0], [67:134]=b, rest 0
__device__ float g_w0b_dev1[256];
__device__ uint4 g_pack[NDEV];      // {cont_f32, lo_idx, hi_idx, 0}
// Transposed weights, padded to output-stride 64 (zeros beyond O).
__device__ float g_Wt_ch1[46 * 64];
__device__ float g_Wt_dev2[67 * 64];
__device__ float g_Wt_fus[94 * 64];
__device__ float g_Wt_c1[106 * 64];
__device__ float g_Wt_c2[63 * 64];
__device__ float g_bpad[5 * 64];

__device__ __forceinline__ float rl(float v, int k) {
    return __uint_as_float(__builtin_amdgcn_readlane(__float_as_uint(v), (unsigned)k));
}

// ---------------------------------------------------------------------------
// Kernel A: pack device rows, build interleaved projected tables, transposed/
// padded weights, packed (W[:,0], b). One thread per output element.
// ---------------------------------------------------------------------------
__global__ __launch_bounds__(256) void prep_kernel(
    const float* __restrict__ devf,
    const float* __restrict__ lang, const float* __restrict__ plat,
    const float* __restrict__ osb, const float* __restrict__ country,
    const float* __restrict__ carrier, const float* __restrict__ brand,
    const float* __restrict__ plat_os,
    const float* __restrict__ Wmsg, const float* __restrict__ bmsg,
    const float* __restrict__ Wdev1, const float* __restrict__ bdev1,
    const float* __restrict__ Wch1, const float* __restrict__ bch1,
    const float* __restrict__ Wdev2, const float* __restrict__ bdev2,
    const float* __restrict__ Wfus, const float* __restrict__ bfus,
    const float* __restrict__ Wc1, const float* __restrict__ bc1,
    const float* __restrict__ Wc2, const float* __restrict__ bc2)
{
    int idx = blockIdx.x * 256 + threadIdx.x;
    if (idx < NDEV) {
        const float4* dr = (const float4*)(devf + (size_t)idx * 8);
        float4 a = dr[0], b4 = dr[1];
        unsigned lo = (unsigned)a.y | ((unsigned)a.z << 8)
                    | ((unsigned)a.w << 16) | ((unsigned)b4.w << 24);
        unsigned hi = (unsigned)b4.x | ((unsigned)b4.y << 9)
                    | ((unsigned)b4.z << 20);
        g_pack[idx] = make_uint4(__float_as_uint(a.x), lo, hi, 0u);
        return;
    }
    idx -= NDEV;
    if (idx < 2 * NP2HALF) {
        int which = idx / NP2HALF;        // 0 = msg, 1 = dev1
        int rem = idx - which * NP2HALF;
        int row = rem >> 6;
        int l = rem & 63;
        int t, r;
        if (row < 50)        { t = 0; r = row; }
        else if (row < 55)   { t = 1; r = row - 50; }
        else if (row < 85)   { t = 2; r = row - 55; }
        else if (row < 285)  { t = 3; r = row - 85; }
        else if (row < 785)  { t = 4; r = row - 285; }
        else if (row < 2785) { t = 5; r = row - 785; }
        else                 { t = 6; r = row - 2785; }
        const float* tab;
        switch (t) {
            case 0: tab = lang; break;    case 1: tab = plat; break;
            case 2: tab = osb; break;     case 3: tab = country; break;
            case 4: tab = carrier; break; case 5: tab = brand; break;
            default: tab = plat_os;
        }
        const float* e = tab + r * 16;
        const float* W = (which ? Wdev1 : Wmsg);
        const float* Wm = W + l * 113 + 1 + 16 * t;
        float m = 0.f;
#pragma unroll
        for (int j = 0; j < 16; j++) m += e[j] * Wm[j];
        float tl = 0.f;
        if (l < 3) {
            const float* Wt2 = W + (64 + l) * 113 + 1 + 16 * t;
#pragma unroll
            for (int j = 0; j < 16; j++) tl += e[j] * Wt2[j];
        }
        (which ? g_P2dev1 : g_P2msg)[rem] =
            __halves2half2(__float2half(m), __float2half(tl));
        return;
    }
    int l = idx - 2 * NP2HALF;
    if (l < 2944) { int k = l >> 6, o = l & 63; g_Wt_ch1[l]  = (o < 27) ? Wch1[o * 46 + k]  : 0.f; return; }
    l -= 2944;
    if (l < 4288) { int k = l >> 6, o = l & 63; g_Wt_dev2[l] = (o < 50) ? Wdev2[o * 67 + k] : 0.f; return; }
    l -= 4288;
    if (l < 6016) { int k = l >> 6, o = l & 63; g_Wt_fus[l]  = (o < 56) ? Wfus[o * 94 + k]  : 0.f; return; }
    l -= 6016;
    if (l < 6784) { int k = l >> 6, o = l & 63; g_Wt_c1[l]   = (o < 63) ? Wc1[o * 106 + k]  : 0.f; return; }
    l -= 6784;
    if (l < 4032) { int k = l >> 6, o = l & 63; g_Wt_c2[l]   = (o < 31) ? Wc2[o * 63 + k]   : 0.f; return; }
    l -= 4032;
    if (l < 320) {
        int which = l >> 6, o = l & 63;
        const float* b; int O;
        switch (which) {
            case 0: b = bch1; O = 27; break;  case 1: b = bdev2; O = 50; break;
            case 2: b = bfus; O = 56; break;  case 3: b = bc1; O = 63; break;
            default: b = bc2; O = 31;
        }
        g_bpad[l] = (o < O) ? b[o] : 0.f;
        return;
    }
    l -= 320;
    if (l < 268) {
        int which = l / 134, k = l - which * 134;
        float* dst = which ? g_w0b_dev1 : g_w0b_msg;
        const float* W = which ? Wdev1 : Wmsg;
        const float* b = which ? bdev1 : bmsg;
        dst[k] = (k < 67) ? W[k * 113] : b[k - 67];
    }
}

// ---------------------------------------------------------------------------
// Kernel B: one wave per edge.
// Phase 1: all 100 neighbor pack rows fetched in 2 per-lane vector gathers
// (one latency exposure), parked in LDS; loop reads them back via uniform
// ds_read_b128 (broadcast, in-order lgkm) -> readfirstlane -> SALU base math
// -> 7 coalesced f16x2 table gathers -> packed-f16 row sum.
// Phase 2: per-edge MLP fully in registers, lane = output neuron.
// ---------------------------------------------------------------------------
__global__ __launch_bounds__(256) void fused_kernel(
    const float* __restrict__ combin_feats, const float* __restrict__ chemb,
    const int* __restrict__ edges, const int* __restrict__ neibrs,
    const float* __restrict__ Wc3, const float* __restrict__ bc3,
    float* __restrict__ out)
{
    __shared__ uint4 s_pack[4][128];
    int gid = blockIdx.x * 256 + threadIdx.x;
    int e = gid >> 6;
    int lane = threadIdx.x & 63;
    int wv = (threadIdx.x >> 6);

    // Fetch all neighbor pack rows: lane j -> neighbor j, neighbor 64+j.
    const int* nb = neibrs + (size_t)e * NNB;
    int n0 = nb[lane];
    int i1 = 64 + lane; if (i1 >= NNB) i1 = NNB - 1;
    int n1 = nb[i1];
    uint4 va = g_pack[n0];
    uint4 vb = g_pack[n1];
    s_pack[wv][lane] = va;
    s_pack[wv][64 + lane] = vb;
    __syncthreads();

    float mw0  = g_w0b_msg[lane];
    float mb   = g_w0b_msg[67 + lane];
    float mw0b = g_w0b_msg[64 + lane];    // valid lane<3; finite otherwise
    float mbb  = g_w0b_msg[131 + lane];

    const __half2* Pl = g_P2msg + lane;
    float acc0 = 0.f, acc1 = 0.f;

#pragma unroll 4
    for (int j = 0; j < NNB; ++j) {
        uint4 r = s_pack[wv][j];                      // uniform-addr broadcast
        unsigned lo = (unsigned)__builtin_amdgcn_readfirstlane((int)r.y);
        unsigned hi = (unsigned)__builtin_amdgcn_readfirstlane((int)r.z);
        float cont = __uint_as_float((unsigned)__builtin_amdgcn_readfirstlane((int)r.x));
        int b0 = ((int)(lo & 255u)) << 6;                  // lang
        int b1 = (50   + (int)((lo >> 8) & 255u)) << 6;    // plat
        int b2 = (55   + (int)((lo >> 16) & 255u)) << 6;   // os
        int b6 = (2785 + (int)(lo >> 24)) << 6;            // plat_os
        int b3 = (85   + (int)(hi & 511u)) << 6;           // country
        int b4 = (285  + (int)((hi >> 9) & 511u)) << 6;    // carrier
        int b5 = (785  + (int)(hi >> 20)) << 6;            // brand
        __half2 h0 = Pl[b0], h1 = Pl[b1], h2 = Pl[b2];
        __half2 h3 = Pl[b3], h4 = Pl[b4], h5 = Pl[b5], h6 = Pl[b6];
        __half2 s01 = __hadd2(h0, h1), s23 = __hadd2(h2, h3), s45 = __hadd2(h4, h5);
        __half2 s = __hadd2(__hadd2(s01, s23), __hadd2(s45, h6));
        float2 f = __half22float2(s);
        float vm = fmaf(cont, mw0, mb) + f.x;
        float vt = fmaf(cont, mw0b, mbb) + f.y;
        acc0 += fmaxf(vm, 0.f);
        acc1 += fmaxf(vt, 0.f);
    }

    float msg_a = acc0 * 0.01f;
    float msg_b = acc1 * 0.01f;   // lanes 0..2: dims 64..66

    // ---- Phase 2: per-edge MLP, all activations in registers ----
    int e0 = edges[2 * e], e1 = edges[2 * e + 1];

    const float* crow = combin_feats + (size_t)e0 * 31;
    int chid = (int)crow[30];
    float cx = 0.f;
    if (lane < 30)      cx = crow[lane];
    else if (lane < 46) cx = chemb[(size_t)chid * 16 + (lane - 30)];

    // d1 = relu(W_dev1 @ dev_x + b) via packed row + interleaved table
    float d1a, d1b;
    {
        uint4 r = g_pack[e1];
        unsigned lo = (unsigned)__builtin_amdgcn_readfirstlane((int)r.y);
        unsigned hi = (unsigned)__builtin_amdgcn_readfirstlane((int)r.z);
        float cont = __uint_as_float((unsigned)__builtin_amdgcn_readfirstlane((int)r.x));
        int b0 = ((int)(lo & 255u)) << 6;
        int b1 = (50   + (int)((lo >> 8) & 255u)) << 6;
        int b2 = (55   + (int)((lo >> 16) & 255u)) << 6;
        int b6 = (2785 + (int)(lo >> 24)) << 6;
        int b3 = (85   + (int)(hi & 511u)) << 6;
        int b4 = (285  + (int)((hi >> 9) & 511u)) << 6;
        int b5 = (785  + (int)(hi >> 20)) << 6;
        const __half2* Ql = g_P2dev1 + lane;
        __half2 h0 = Ql[b0], h1 = Ql[b1], h2 = Ql[b2];
        __half2 h3 = Ql[b3], h4 = Ql[b4], h5 = Ql[b5], h6 = Ql[b6];
        __half2 s01 = __hadd2(h0, h1), s23 = __hadd2(h2, h3), s45 = __hadd2(h4, h5);
        __half2 s = __hadd2(__hadd2(s01, s23), __hadd2(s45, h6));
        float2 f = __half22float2(s);
        float vm = fmaf(cont, g_w0b_dev1[lane], g_w0b_dev1[67 + lane]) + f.x;
        float vt = fmaf(cont, g_w0b_dev1[64 + lane], g_w0b_dev1[131 + lane]) + f.y;
        d1a = fmaxf(vm, 0.f);
        d1b = fmaxf(vt, 0.f);
    }

    // ch = relu(W_ch1 @ combin_x + b)   I=46, O=27
    float s = g_bpad[lane];
    for (int k = 0; k < 46; k++) s += rl(cx, k) * g_Wt_ch1[k * 64 + lane];
    float ch = fmaxf(s, 0.f);

    // d2 = relu(W_dev2 @ d1 + b)        I=67, O=50
    s = g_bpad[64 + lane];
    for (int k = 0; k < 64; k++) s += rl(d1a, k) * g_Wt_dev2[k * 64 + lane];
    for (int k = 0; k < 3; k++)  s += rl(d1b, k) * g_Wt_dev2[(64 + k) * 64 + lane];
    float d2 = fmaxf(s, 0.f);

    // fus = relu(W_fus @ [ch|msg] + b)  I=94, O=56
    s = g_bpad[128 + lane];
    for (int k = 0; k < 27; k++) s += rl(ch, k) * g_Wt_fus[k * 64 + lane];
    for (int k = 0; k < 64; k++) s += rl(msg_a, k) * g_Wt_fus[(27 + k) * 64 + lane];
    for (int k = 0; k < 3; k++)  s += rl(msg_b, k) * g_Wt_fus[(91 + k) * 64 + lane];
    float fus = fmaxf(s, 0.f);

    // h1 = relu(W_c1 @ [fus|d2] + b)    I=106, O=63
    s = g_bpad[192 + lane];
    for (int k = 0; k < 56; k++) s += rl(fus, k) * g_Wt_c1[k * 64 + lane];
    for (int k = 0; k < 50; k++) s += rl(d2, k) * g_Wt_c1[(56 + k) * 64 + lane];
    float h1 = fmaxf(s, 0.f);

    // h2 = relu(W_c2 @ h1 + b)          I=63, O=31
    s = g_bpad[256 + lane];
    for (int k = 0; k < 63; k++) s += rl(h1, k) * g_Wt_c2[k * 64 + lane];
    float h2 = fmaxf(s, 0.f);

    // out = W_c3 @ h2 + b  (wave butterfly reduction)
    float t = (lane < 31) ? h2 * Wc3[lane] : 0.f;
    for (int off = 32; off; off >>= 1) t += __shfl_xor(t, off);
    if (lane == 0) out[e] = t + bc3[0];
}

extern "C" void kernel_launch(void* const* d_in, const int* in_sizes, int n_in,
                              void* d_out, int out_size, void* d_ws, size_t ws_size,
                              hipStream_t stream) {
    const float* combin   = (const float*)d_in[0];
    const float* devf     = (const float*)d_in[1];
    const float* chemb    = (const float*)d_in[2];
    const float* lang     = (const float*)d_in[3];
    const float* plat     = (const float*)d_in[4];
    const float* osb      = (const float*)d_in[5];
    const float* country  = (const float*)d_in[6];
    const float* carrier  = (const float*)d_in[7];
    const float* brand    = (const float*)d_in[8];
    const float* plat_os  = (const float*)d_in[9];
    const float* Wch1 = (const float*)d_in[10]; const float* bch1 = (const float*)d_in[11];
    const float* Wmsg = (const float*)d_in[12]; const float* bmsg = (const float*)d_in[13];
    const float* Wfus = (const float*)d_in[14]; const float* bfus = (const float*)d_in[15];
    const float* Wdev1 = (const float*)d_in[16]; const float* bdev1 = (const float*)d_in[17];
    const float* Wdev2 = (const float*)d_in[18]; const float* bdev2 = (const float*)d_in[19];
    const float* Wc1 = (const float*)d_in[20]; const float* bc1 = (const float*)d_in[21];
    const float* Wc2 = (const float*)d_in[22]; const float* bc2 = (const float*)d_in[23];
    const float* Wc3 = (const float*)d_in[24]; const float* bc3 = (const float*)d_in[25];
    const int* edges  = (const int*)d_in[26];
    const int* neibrs = (const int*)d_in[27];
    float* out = (float*)d_out;

    long long prep_threads = (long long)NDEV + 2LL * NP2HALF + 24064 + 320 + 268;
    int prep_blocks = (int)((prep_threads + 255) / 256);
    prep_kernel<<<prep_blocks, 256, 0, stream>>>(
        devf, lang, plat, osb, country, carrier, brand, plat_os,
        Wmsg, bmsg, Wdev1, bdev1, Wch1, bch1, Wdev2, bdev2,
        Wfus, bfus, Wc1, bc1, Wc2, bc2);

    fused_kernel<<<BATCH / 4, 256, 0, stream>>>(
        combin, chemb, edges, neibrs, Wc3, bc3, out);
}